// Round 12
// baseline (41.703 us; speedup 1.0000x reference)
//
#include <hip/hip_runtime.h>
#include <stdint.h>

// out[b,p] = mean_d( probes[p,d] <= X[b,d] ? 1.0 : X[b,d] )
// B=2048, P=512, D=256, f32. Exact-mask math (validated R6-R11):
//   y = 1-x (exact); q1 = fma(p,-2^24,2^24)+1 (exact int)
//   m2 = clamp(pk_fma(y, -2^24, q1)) = clamp(2^24(x-p)+1) in {0,1}, 1 iff p<=x
//   acc += m*y ; out = (SX[b] + sum m*y)/256,  SX[b] = sum_d x  (prep kernel)
// R12 structure (lane=batch / s_load-probe stream):
//   wave = 64 batches (lane=row) x 8 probes; y-chunk read from LDS once per
//   64-d chunk, reused across probes (6x fewer LDS instr than R10); q1 rows
//   streamed through the SCALAR pipe (uniform addr -> s_load) as the one SGPR
//   operand of v_pk_fma_f32. No barriers in the compute loop; direct stores.

#define BATCH  2048
#define NPROBE 512
#define DIM    256

typedef float f4 __attribute__((ext_vector_type(4)));
typedef float f2 __attribute__((ext_vector_type(2)));

#define KF 16777216.0f
#define Q1_OFF 0
#define SX_OFF (NPROBE * DIM)                 // f32 units
#define WS_NEED ((size_t)((SX_OFF + BATCH) * 4))

// ---------------- prep: Q1 transform + per-row X sums ----------------
__global__ __launch_bounds__(512)
void prep_kernel(const float* __restrict__ X, const float* __restrict__ Pr,
                 float* __restrict__ ws) {
  const int wv   = blockIdx.x * 8 + (threadIdx.x >> 6);   // 0..2559
  const int lane = threadIdx.x & 63;
  if (wv < BATCH) {
    f4 v = *(const f4*)(X + (size_t)wv * DIM + 4 * lane);
    float s = (v[0] + v[1]) + (v[2] + v[3]);
    #pragma unroll
    for (int off = 32; off; off >>= 1) s += __shfl_xor(s, off, 64);
    if (lane == 0) ws[SX_OFF + wv] = s;
  } else {
    const int p = wv - BATCH;                 // < 512 by grid size
    f4 v = *(const f4*)(Pr + (size_t)p * DIM + 4 * lane);
    f4 q;
    #pragma unroll
    for (int e = 0; e < 4; ++e)
      q[e] = __builtin_fmaf(v[e], -KF, KF) + 1.0f;        // exact int
    *(f4*)(ws + Q1_OFF + (size_t)p * DIM + 4 * lane) = q;
  }
}

// ---------------- main ----------------
__global__ __launch_bounds__(512, 2)
void yoneda_main(const float* __restrict__ X, const float* __restrict__ ws,
                 float* __restrict__ out) {
  // y tile [64 rows][260 f32] (+16B pad -> lane stride 1040B == 16B mod 128:
  // canonical conflict-free b128 pattern). 66.6 KiB.
  __shared__ float yl[64 * 260];

  const int tid = threadIdx.x;
  const int p0  = blockIdx.x * 64;
  const int b0  = blockIdx.y * 64;

  // stage y = 1 - x (reg-staged; transform prevents global_load_lds)
  #pragma unroll
  for (int s = 0; s < 8; ++s) {
    int idx = s * 512 + tid;
    int r = idx >> 6, c = idx & 63;
    f4 v = *(const f4*)(X + (size_t)(b0 + r) * DIM + 4 * c);
    f4 y;
    #pragma unroll
    for (int e = 0; e < 4; ++e) y[e] = 1.0f - v[e];        // exact
    *(f4*)&yl[r * 260 + 4 * c] = y;                        // stride-16B: free
  }

  const int w = __builtin_amdgcn_readfirstlane(tid >> 6);  // wave id 0..7 (uniform!)
  const int l = tid & 63;                                  // lane = batch row
  const float* q1w = ws + Q1_OFF + (size_t)(p0 + w * 8) * DIM;  // uniform base
  const float sxv  = ws[SX_OFF + b0 + l];                  // per-lane, coalesced

  f2 acc[8];
  #pragma unroll
  for (int j = 0; j < 8; ++j) acc[j] = (f2){0.0f, 0.0f};
  const f2 mK2 = {-KF, -KF};

  __syncthreads();                    // y tile ready; no barriers after this

  #pragma unroll 1
  for (int dc = 0; dc < 4; ++dc) {
    f4 yq[16];                        // this lane's 64 d of y
    #pragma unroll
    for (int i = 0; i < 16; ++i)
      yq[i] = *(const f4*)&yl[l * 260 + dc * 64 + 4 * i];
    #pragma unroll
    for (int jj = 0; jj < 8; ++jj) {
      const f2* q2p = (const f2*)(q1w + jj * DIM + dc * 64);  // uniform -> s_load
      #pragma unroll
      for (int u = 0; u < 32; ++u) {
        f2 q2 = q2p[u];
        f2 y2 = (u & 1) ? (f2){yq[u >> 1][2], yq[u >> 1][3]}
                        : (f2){yq[u >> 1][0], yq[u >> 1][1]};
        f2 m;
        asm("v_pk_fma_f32 %0, %1, %2, %3 clamp"
            : "=v"(m) : "v"(y2), "v"(mK2), "s"(q2));
        asm("v_pk_fma_f32 %0, %1, %2, %0"
            : "+v"(acc[jj]) : "v"(m), "v"(y2));
      }
    }
  }

  // ---- transpose via LDS (reuse tile region) -> coalesced stores
  __syncthreads();                    // all y reads done
  #pragma unroll
  for (int jj = 0; jj < 8; ++jj)
    yl[(w * 8 + jj) * 65 + l] = sxv + (acc[jj][0] + acc[jj][1]);  // stride-1: free
  __syncthreads();
  const float inv = 1.0f / 256.0f;
  const int r  = tid >> 3;
  const int pb = (tid & 7) * 8;
  f4 o0, o1;
  #pragma unroll
  for (int j = 0; j < 4; ++j) {
    o0[j] = yl[(pb + j) * 65 + r] * inv;       // <=2-way conflicts: free
    o1[j] = yl[(pb + 4 + j) * 65 + r] * inv;
  }
  size_t ro = (size_t)(b0 + r) * NPROBE + p0 + pb;
  *(f4*)(out + ro)     = o0;                   // 8 thr x 32B = 256B segments
  *(f4*)(out + ro + 4) = o1;
}

// ---------------- fallback (R10 kernel, passed) if ws too small ----------------
__global__ __launch_bounds__(1024, 4)
void yoneda_fb(const float* __restrict__ X, const float* __restrict__ Pr,
               float* __restrict__ out) {
  __shared__ float lds[32768];
  const int tid = threadIdx.x;
  const int b0 = blockIdx.y * 64, p0 = blockIdx.x * 64;
  #pragma unroll
  for (int s = 0; s < 4; ++s) {
    int idx = s * 1024 + tid;
    int r = idx >> 6, q = idx & 63;
    int slot = (q & 56) | ((q ^ r) & 7);
    f4 xv = *(const f4*)(X  + (size_t)(b0 + r) * DIM + 4 * q);
    f4 pv = *(const f4*)(Pr + (size_t)(p0 + r) * DIM + 4 * q);
    f4 yv, qv;
    #pragma unroll
    for (int e = 0; e < 4; ++e) {
      yv[e] = 1.0f - xv[e];
      qv[e] = __builtin_fmaf(pv[e], -KF, KF) + 1.0f;
    }
    *(f4*)&lds[r * 256 + 4 * slot]         = yv;
    *(f4*)&lds[16384 + r * 256 + 4 * slot] = qv;
  }
  const int wv = tid >> 6, g2 = wv >> 1, ph = wv & 1;
  const int gtid = tid & 63, tb = gtid >> 3, tp = gtid & 7;
  int xrow[8], prow[4];
  #pragma unroll
  for (int i = 0; i < 8; ++i) xrow[i] = (tb + 8 * i) * 256 + g2 * 32;
  #pragma unroll
  for (int j = 0; j < 4; ++j) prow[j] = 16384 + (ph * 32 + tp + 8 * j) * 256 + g2 * 32;
  f2 acc2[8][4], accy2[8];
  #pragma unroll
  for (int i = 0; i < 8; ++i) {
    accy2[i] = (f2){0.0f, 0.0f};
    #pragma unroll
    for (int j = 0; j < 4; ++j) acc2[i][j] = (f2){0.0f, 0.0f};
  }
  const f2 mK2 = {-KF, -KF};
  __syncthreads();
  #pragma unroll 1
  for (int s = 0; s < 8; ++s) {
    const int xo = 4 * (s ^ tb), po = 4 * (s ^ tp);
    f4 pv[4];
    #pragma unroll
    for (int j = 0; j < 4; ++j) pv[j] = *(const f4*)&lds[prow[j] + po];
    #pragma unroll
    for (int i = 0; i < 8; ++i) {
      f4 yv = *(const f4*)&lds[xrow[i] + xo];
      f2 ya = {yv[0], yv[1]}, yc = {yv[2], yv[3]};
      accy2[i] += ya; accy2[i] += yc;
      #pragma unroll
      for (int j = 0; j < 4; ++j) {
        f2 pa = {pv[j][0], pv[j][1]}, pc = {pv[j][2], pv[j][3]};
        f2 ma, mc;
        asm("v_pk_fma_f32 %0, %1, %2, %3 clamp" : "=v"(ma) : "v"(ya), "v"(mK2), "v"(pa));
        asm("v_pk_fma_f32 %0, %1, %2, %0" : "+v"(acc2[i][j]) : "v"(ma), "v"(ya));
        asm("v_pk_fma_f32 %0, %1, %2, %3 clamp" : "=v"(mc) : "v"(yc), "v"(mK2), "v"(pc));
        asm("v_pk_fma_f32 %0, %1, %2, %0" : "+v"(acc2[i][j]) : "v"(mc), "v"(yc));
      }
    }
  }
  __syncthreads();
  const int tbx = tb << 2, obase = tb * 64 + ph * 32 + tp, gseg = g2 << 12;
  #pragma unroll
  for (int i = 0; i < 8; ++i) {
    float sxg = 32.0f - (accy2[i][0] + accy2[i][1]);
    #pragma unroll
    for (int j = 0; j < 4; ++j) {
      int o = obase + 512 * i + 8 * j;
      lds[gseg + (o ^ tbx)] = sxg + acc2[i][j][0] + acc2[i][j][1];
    }
  }
  __syncthreads();
  const float inv = 1.0f / 256.0f;
  const int fold = ((tid >> 5) & 7) << 2;
  #pragma unroll
  for (int k = 0; k < 2; ++k) {
    int o = 2 * (k * 1024 + tid);
    int a = o ^ fold;
    f2 v = *(const f2*)&lds[a];
    #pragma unroll
    for (int g = 1; g < 8; ++g) v += *(const f2*)&lds[(g << 12) + a];
    v *= inv;
    int row = o >> 6, col = o & 63;
    *(f2*)&out[(size_t)(b0 + row) * NPROBE + p0 + col] = v;
  }
}

extern "C" void kernel_launch(void* const* d_in, const int* in_sizes, int n_in,
                              void* d_out, int out_size, void* d_ws, size_t ws_size,
                              hipStream_t stream) {
  const float* X  = (const float*)d_in[0];   // (2048, 256) f32
  const float* Pr = (const float*)d_in[1];   // (512, 256)  f32
  float* outp = (float*)d_out;               // (2048, 512) f32

  if (ws_size >= WS_NEED) {
    float* ws = (float*)d_ws;
    prep_kernel<<<320, 512, 0, stream>>>(X, Pr, ws);
    dim3 grid(NPROBE / 64, BATCH / 64);      // (8, 32) = 256 blocks, 1/CU
    yoneda_main<<<grid, 512, 0, stream>>>(X, ws, outp);
  } else {
    dim3 grid(NPROBE / 64, BATCH / 64);
    yoneda_fb<<<grid, 1024, 0, stream>>>(X, Pr, outp);
  }
}

// Round 13
// 29.509 us; speedup vs baseline: 1.4132x; 1.4132x over previous
//
#include <hip/hip_runtime.h>
#include <stdint.h>

// out[b,p] = mean_d( probes[p,d] <= X[b,d] ? 1.0 : X[b,d] )
// B=2048, P=512, D=256, f32. Exact-mask math (validated R6-R11):
//   q1 = fma(p, -2^24, 1)  (exact odd int, single op)
//   m2 = clamp(pk_fma(x, 2^24, q1)) = clamp(2^24(x-p)+1) in {0,1}, 1 iff p<=x
//   y = 1-x (exact, in-loop);  acc += m*y;  partial = (32 - Sum y) + Sum m*y
// R13 structure: 2 blocks/CU (the untested knob). Tile 64b x 32p, grid 512,
// 512 thr (8 waves = 8 d-slices of 32d), D chunked 2x128 (LDS 73 KiB -> two
// co-resident blocks; one block computes while the other stages/barriers).
// X staged raw via global_load_lds (async, source-swizzled); P reg-staged
// with 1-op transform. Combine via stride-292/9 overlay (<=2-way banks).

#define BATCH  2048
#define NPROBE 512
#define DIM    256
#define KF 16777216.0f

typedef float f4 __attribute__((ext_vector_type(4)));
typedef float f2 __attribute__((ext_vector_type(2)));

static __device__ __forceinline__ void gl_lds16(const void* g, void* l) {
  __builtin_amdgcn_global_load_lds(
      (const __attribute__((address_space(1))) void*)g,
      (__attribute__((address_space(3))) void*)l, 16, 0, 0);
}

__global__ __launch_bounds__(512, 4)
void yoneda_kernel(const float* __restrict__ X, const float* __restrict__ Pr,
                   float* __restrict__ out) {
  // [0,8192): X-chunk [64r][32 quads] (raw x); [8192,12288): P-chunk [32r][32q] (q1)
  // combine overlay: lds[row*292 + col*9 + w], max 18688 f32 = 73 KiB
  __shared__ float lds[18688];
  float* Ps = lds + 8192;

  const int tid = threadIdx.x;
  const int p0 = blockIdx.x * 32, b0 = blockIdx.y * 64;
  const int w  = tid >> 6;          // wave 0..7 = d-slice {w+8s quads}
  const int tb = (tid >> 3) & 7;    // rows tb+8i, i<8
  const int tp = tid & 7;           // cols tp+8j, j<4

  f2 acc2[8][4], accy2[8];
  #pragma unroll
  for (int i = 0; i < 8; ++i) {
    accy2[i] = (f2){0.0f, 0.0f};
    #pragma unroll
    for (int j = 0; j < 4; ++j) acc2[i][j] = (f2){0.0f, 0.0f};
  }
  const f2 K2 = {KF, KF};

  #pragma unroll 1
  for (int c = 0; c < 2; ++c) {
    // ---- X: async global->LDS, swizzle on SOURCE (slot l holds quad l^(r&7))
    #pragma unroll
    for (int s = 0; s < 4; ++s) {
      int idx = s * 512 + tid;          // quad in chunk [0,2048)
      int r = idx >> 5, l = idx & 31;
      gl_lds16(X + (size_t)(b0 + r) * DIM + c * 128 + 4 * (l ^ (r & 7)),
               &lds[idx * 4]);
    }
    // ---- P: reg-staged, q1 = fma(p,-K,1) exact, write-swizzled
    #pragma unroll
    for (int s = 0; s < 2; ++s) {
      int idx = s * 512 + tid;          // quad in chunk [0,1024)
      int r = idx >> 5, l = idx & 31;
      f4 p = *(const f4*)(Pr + (size_t)(p0 + r) * DIM + c * 128 + 4 * l);
      f4 q;
      #pragma unroll
      for (int e = 0; e < 4; ++e) q[e] = __builtin_fmaf(p[e], -KF, 1.0f);
      *(f4*)&Ps[(r * 32 + (l ^ (r & 7))) * 4] = q;
    }
    __syncthreads();                    // drain staging (vmcnt + lgkm)

    #pragma unroll
    for (int s = 0; s < 4; ++s) {
      const int l = w + 8 * s;          // this wave's quad (global in chunk)
      f4 pv[4];
      #pragma unroll
      for (int j = 0; j < 4; ++j)
        pv[j] = *(const f4*)&Ps[((tp + 8 * j) * 32 + (l ^ tp)) * 4];
      #pragma unroll
      for (int i = 0; i < 8; ++i) {
        f4 xv = *(const f4*)&lds[((tb + 8 * i) * 32 + (l ^ tb)) * 4];
        f2 xa = {xv[0], xv[1]}, xc = {xv[2], xv[3]};
        f2 ya = (f2){1.0f, 1.0f} - xa;  // exact
        f2 yc = (f2){1.0f, 1.0f} - xc;
        accy2[i] += ya;
        accy2[i] += yc;
        #pragma unroll
        for (int j = 0; j < 4; ++j) {
          f2 pa = {pv[j][0], pv[j][1]}, pc = {pv[j][2], pv[j][3]};
          f2 ma, mc;
          asm("v_pk_fma_f32 %0, %1, %2, %3 clamp"
              : "=v"(ma) : "v"(xa), "v"(K2), "v"(pa));
          asm("v_pk_fma_f32 %0, %1, %2, %0"
              : "+v"(acc2[i][j]) : "v"(ma), "v"(ya));
          asm("v_pk_fma_f32 %0, %1, %2, %3 clamp"
              : "=v"(mc) : "v"(xc), "v"(K2), "v"(pc));
          asm("v_pk_fma_f32 %0, %1, %2, %0"
              : "+v"(acc2[i][j]) : "v"(mc), "v"(yc));
        }
      }
    }
    __syncthreads();                    // chunk reads done before restage/overlay
  }

  // ---- combine 8 d-slice partials; overlay idx = row*292 + col*9 + w
  // banks: (4row + 9col + w) mod 32 -> <=2 lanes/bank on write & read (checked)
  #pragma unroll
  for (int i = 0; i < 8; ++i) {
    float sxp = 32.0f - (accy2[i][0] + accy2[i][1]);   // Sum_slice x
    #pragma unroll
    for (int j = 0; j < 4; ++j) {
      int row = tb + 8 * i, col = tp + 8 * j;
      lds[row * 292 + col * 9 + w] = sxp + acc2[i][j][0] + acc2[i][j][1];
    }
  }
  __syncthreads();
  const float inv = 1.0f / 256.0f;
  #pragma unroll
  for (int k = 0; k < 4; ++k) {
    int o = tid + 512 * k;              // output index in tile [0,2048)
    int row = o >> 5, col = o & 31;
    int base = row * 292 + col * 9;
    float v = lds[base];
    #pragma unroll
    for (int g = 1; g < 8; ++g) v += lds[base + g];   // ascending -> deterministic
    out[(size_t)(b0 + row) * NPROBE + p0 + col] = v * inv;
  }
}

extern "C" void kernel_launch(void* const* d_in, const int* in_sizes, int n_in,
                              void* d_out, int out_size, void* d_ws, size_t ws_size,
                              hipStream_t stream) {
  const float* X  = (const float*)d_in[0];   // (2048, 256) f32
  const float* Pr = (const float*)d_in[1];   // (512, 256)  f32
  float* outp = (float*)d_out;               // (2048, 512) f32
  dim3 grid(NPROBE / 32, BATCH / 64);        // (16, 32) = 512 blocks = 2/CU
  yoneda_kernel<<<grid, 512, 0, stream>>>(X, Pr, outp);
}